// Round 1
// baseline (917.073 us; speedup 1.0000x reference)
//
#include <hip/hip_runtime.h>

namespace {
constexpr int kB = 16, kC = 64, kN = 1024, kT = 64, kNB = 32;
}

__device__ __forceinline__ float tanh_fast(float x) {
    // tanh(x) = 1 - 2/(e^{2x}+1); handles +-inf gracefully (saturates to +-1)
    float e = __expf(2.0f * x);
    return 1.0f - 2.0f * __builtin_amdgcn_rcpf(e + 1.0f);
}

__global__ __launch_bounds__(256, 2) void rnn_fused_kernel(
    const float* __restrict__ x, const float* __restrict__ w1,
    const float* __restrict__ b1, const float* __restrict__ w2,
    const float* __restrict__ b2, float* __restrict__ out)
{
    // w1t[f][v] = w1[v][f]; pad 65 so broadcast reads & transposed writes are conflict-free
    __shared__ __align__(16) float w1t[kC][kC + 1];
    __shared__ __align__(16) float w2t[kC][kC + 1];
    __shared__ __align__(16) float bsum[kC];
    __shared__ __align__(16) float xs[4][kC][kNB];  // 4 timesteps of x, then reused as out buffer
    __shared__ __align__(16) float Hs[kC][kNB];     // carry state across 4-step groups

    const int tid = threadIdx.x;
    const int bid = blockIdx.x;
    const int b   = bid >> 5;          // / (kN/kNB)
    const int n0  = (bid & 31) * kNB;

    // stage weights: coalesced global read, transposed LDS write (2-way conflict = free)
    #pragma unroll
    for (int k = 0; k < 16; ++k) {
        const int idx = tid + 256 * k;       // 4096 elements
        const int v = idx >> 6, f = idx & 63;
        w1t[f][v] = w1[idx];
        w2t[f][v] = w2[idx];
    }
    if (tid < kC) bsum[tid] = b1[tid] + b2[tid];
    #pragma unroll
    for (int k = 0; k < 8; ++k) {
        reinterpret_cast<float*>(Hs)[tid + 256 * k] = 0.0f;  // h0 = 0
    }
    __syncthreads();

    const int v  = tid >> 2;         // output channel this thread owns
    const int ng = (tid & 3) * 8;    // 8 n's this thread owns
    const float bs = bsum[v];

    for (int tg = 0; tg < kT / 4; ++tg) {
        // ---- A: gather x for 4 timesteps: xs[tt][f][n] = x[b,f,n0+n,4tg+tt]
        #pragma unroll
        for (int k = 0; k < 8; ++k) {
            const int lin = tid + 256 * k;   // 2048 (f,n) pairs
            const int f = lin >> 5, n = lin & 31;
            const float4 xv = *reinterpret_cast<const float4*>(
                x + ((b * kC + f) * kN + n0 + n) * kT + tg * 4);
            xs[0][f][n] = xv.x;
            xs[1][f][n] = xv.y;
            xs[2][f][n] = xv.z;
            xs[3][f][n] = xv.w;
        }
        __syncthreads();

        // ---- C: 4 sequential timesteps
        #pragma unroll
        for (int tt = 0; tt < 4; ++tt) {
            // previous state: Hs for the first step of the group, else the
            // h-values written into the already-consumed xs plane tt-1
            const float* hsrc = (tt == 0) ? &Hs[0][0] : &xs[tt - 1][0][0];

            float acc[8];
            #pragma unroll
            for (int j = 0; j < 8; ++j) acc[j] = bs;

            // xw part: sum_f w1[v,f] * x[f,n,t]
            #pragma unroll 4
            for (int f = 0; f < kC; ++f) {
                const float w = w1t[f][v];
                const float4 xa = *reinterpret_cast<const float4*>(&xs[tt][f][ng]);
                const float4 xb = *reinterpret_cast<const float4*>(&xs[tt][f][ng + 4]);
                acc[0] = fmaf(w, xa.x, acc[0]);
                acc[1] = fmaf(w, xa.y, acc[1]);
                acc[2] = fmaf(w, xa.z, acc[2]);
                acc[3] = fmaf(w, xa.w, acc[3]);
                acc[4] = fmaf(w, xb.x, acc[4]);
                acc[5] = fmaf(w, xb.y, acc[5]);
                acc[6] = fmaf(w, xb.z, acc[6]);
                acc[7] = fmaf(w, xb.w, acc[7]);
            }
            // recurrent part: sum_u w2[v,u] * h[u,n]
            #pragma unroll 4
            for (int u = 0; u < kC; ++u) {
                const float w = w2t[u][v];
                const float4 ha = *reinterpret_cast<const float4*>(hsrc + u * kNB + ng);
                const float4 hb = *reinterpret_cast<const float4*>(hsrc + u * kNB + ng + 4);
                acc[0] = fmaf(w, ha.x, acc[0]);
                acc[1] = fmaf(w, ha.y, acc[1]);
                acc[2] = fmaf(w, ha.z, acc[2]);
                acc[3] = fmaf(w, ha.w, acc[3]);
                acc[4] = fmaf(w, hb.x, acc[4]);
                acc[5] = fmaf(w, hb.y, acc[5]);
                acc[6] = fmaf(w, hb.z, acc[6]);
                acc[7] = fmaf(w, hb.w, acc[7]);
            }

            float4 o0, o1;
            o0.x = tanh_fast(acc[0]);
            o0.y = tanh_fast(acc[1]);
            o0.z = tanh_fast(acc[2]);
            o0.w = tanh_fast(acc[3]);
            o1.x = tanh_fast(acc[4]);
            o1.y = tanh_fast(acc[5]);
            o1.z = tanh_fast(acc[6]);
            o1.w = tanh_fast(acc[7]);

            __syncthreads();  // all reads of xs[tt] / hsrc complete
            *reinterpret_cast<float4*>(&xs[tt][v][ng])     = o0;  // out buffer + next-step state
            *reinterpret_cast<float4*>(&xs[tt][v][ng + 4]) = o1;
            if (tt == 3) {  // carry across the group boundary (xs gets reloaded)
                *reinterpret_cast<float4*>(&Hs[v][ng])     = o0;
                *reinterpret_cast<float4*>(&Hs[v][ng + 4]) = o1;
            }
            __syncthreads();  // new h visible to all
        }

        // ---- D: write 4 timesteps of output as float4 (full 16B granules)
        #pragma unroll
        for (int k = 0; k < 8; ++k) {
            const int lin = tid + 256 * k;
            const int vv = lin >> 5, n = lin & 31;
            float4 o;
            o.x = xs[0][vv][n];
            o.y = xs[1][vv][n];
            o.z = xs[2][vv][n];
            o.w = xs[3][vv][n];
            *reinterpret_cast<float4*>(
                out + ((b * kC + vv) * kN + n0 + n) * kT + tg * 4) = o;
        }
        __syncthreads();  // xs free for next group's gather
    }
}

extern "C" void kernel_launch(void* const* d_in, const int* in_sizes, int n_in,
                              void* d_out, int out_size, void* d_ws, size_t ws_size,
                              hipStream_t stream) {
    const float* x  = (const float*)d_in[0];
    const float* w1 = (const float*)d_in[1];
    const float* b1 = (const float*)d_in[2];
    const float* w2 = (const float*)d_in[3];
    const float* b2 = (const float*)d_in[4];
    float* out = (float*)d_out;
    dim3 grid(kB * (kN / kNB));   // 512 blocks
    dim3 block(256);
    hipLaunchKernelGGL(rnn_fused_kernel, grid, block, 0, stream,
                       x, w1, b1, w2, b2, out);
}

// Round 2
// 640.897 us; speedup vs baseline: 1.4309x; 1.4309x over previous
//
#include <hip/hip_runtime.h>
#include <hip/hip_bf16.h>

namespace {
constexpr int kB = 16, kC = 64, kN = 1024, kT = 64;
constexpr size_t kWsNeed = (size_t)kB * kC * kN * kT * 4;  // 268435456
}

typedef short bf16x8 __attribute__((ext_vector_type(8)));
typedef float f32x4 __attribute__((ext_vector_type(4)));

__device__ __forceinline__ float tanh_fast(float x) {
    float e = __expf(2.0f * x);
    return 1.0f - 2.0f * __builtin_amdgcn_rcpf(e + 1.0f);
}

__device__ __forceinline__ unsigned short bf16_rnd(float f) {
    unsigned int u = __float_as_uint(f);
    u = (u + 0x7FFFu + ((u >> 16) & 1u)) >> 16;   // RTNE
    return (unsigned short)u;
}
__device__ __forceinline__ float bf16_to_f32(unsigned short s) {
    return __uint_as_float(((unsigned int)s) << 16);
}
__device__ __forceinline__ void split3(float v, unsigned short& h,
                                       unsigned short& m, unsigned short& l) {
    h = bf16_rnd(v);
    float r = v - bf16_to_f32(h);
    m = bf16_rnd(r);
    float r2 = r - bf16_to_f32(m);
    l = bf16_rnd(r2);
}

// ws fragment layout: element (b, nt, t, vt, m, lane, reg) at
//   ((((b*32+nt)*64 + t)*4 + vt)*2 + m)*256 + lane*4 + reg
// with 16x16x32 C/D map: lane = (n&15) + 16*((v&15)>>2), reg = v&3,
// vt = v>>4, m = (n_local)>>4   [m89-verified mapping]

// ---------------- Kernel A: xw = w1 @ x + (b1 + b2), fp32 VALU ----------------
__global__ __launch_bounds__(256, 2) void xw_gemm(
    const float* __restrict__ x, const float* __restrict__ w1,
    const float* __restrict__ b1, const float* __restrict__ b2,
    float* __restrict__ ws)
{
    __shared__ __align__(16) float w1t[64][72];      // [f][v], padded rows (18.4KB)
    __shared__ __align__(16) float xs[16][32][20];   // [f-chunk][n][t16 + pad] (40KB)

    const int tid = threadIdx.x;
    const int bid = blockIdx.x;
    const int tc = bid & 3;            // t-chunk (16 t's)
    const int nt = (bid >> 2) & 31;    // n-tile (32 n's)
    const int b  = bid >> 7;
    const int n0 = nt * 32;

    // stage w1 transposed: w1t[f][v] = w1[v*64+f]
    #pragma unroll
    for (int k = 0; k < 16; ++k) {
        int idx = tid + 256 * k;       // 4096
        int v = idx >> 6, f = idx & 63;
        w1t[f][v] = w1[idx];
    }

    const int vg = tid >> 5;           // 0..7  -> v0 = vg*8
    const int n  = tid & 31;
    const int v0 = vg * 8;
    const int p  = (n >> 3) & 3;       // t-quad swizzle key for this column

    float bias[8];
    #pragma unroll
    for (int vj = 0; vj < 8; ++vj) bias[vj] = b1[v0 + vj] + b2[v0 + vj];

    float acc[8][4][4];                // [vj][phys-quad][elem]
    #pragma unroll
    for (int vj = 0; vj < 8; ++vj)
        #pragma unroll
        for (int q = 0; q < 4; ++q)
            #pragma unroll
            for (int j = 0; j < 4; ++j) acc[vj][q][j] = bias[vj];

    for (int fc = 0; fc < 4; ++fc) {
        __syncthreads();   // protect xs from previous chunk's readers
        // stage 16 f x 32 n x 16 t
        #pragma unroll
        for (int r = 0; r < 8; ++r) {
            int slot = tid + 256 * r;            // 2048 float4 slots
            int f = slot >> 7, nn = (slot >> 2) & 31, tq = slot & 3;
            const float4 xv = *reinterpret_cast<const float4*>(
                x + ((size_t)(b * 64 + fc * 16 + f) * 1024 + n0 + nn) * 64
                  + tc * 16 + tq * 4);
            int pp = (nn >> 3) & 3;
            *reinterpret_cast<float4*>(&xs[f][nn][((tq ^ pp) * 4)]) = xv;
        }
        __syncthreads();

        for (int f = 0; f < 16; ++f) {
            const int ff = fc * 16 + f;
            const float4 wA = *reinterpret_cast<const float4*>(&w1t[ff][v0]);
            const float4 wB = *reinterpret_cast<const float4*>(&w1t[ff][v0 + 4]);
            float wv[8] = {wA.x, wA.y, wA.z, wA.w, wB.x, wB.y, wB.z, wB.w};
            #pragma unroll
            for (int q = 0; q < 4; ++q) {
                const float4 xv = *reinterpret_cast<const float4*>(&xs[f][n][q * 4]);
                float xe[4] = {xv.x, xv.y, xv.z, xv.w};
                #pragma unroll
                for (int vj = 0; vj < 8; ++vj)
                    #pragma unroll
                    for (int j = 0; j < 4; ++j)
                        acc[vj][q][j] = fmaf(wv[vj], xe[j], acc[vj][q][j]);
            }
        }
    }

    // epilogue: store in MFMA C-fragment order, coalesced dwordx4
    const int vt  = vg >> 1;
    const int m   = n >> 4;
    const int nl  = n & 15;
    const size_t tilecol = ((size_t)(b * 32 + nt) * 64) * 2048;  // *4vt*2m*256
    #pragma unroll
    for (int q = 0; q < 4; ++q) {
        #pragma unroll
        for (int jj = 0; jj < 4; ++jj) {
            const int t = tc * 16 + ((q ^ p) * 4) + jj;
            #pragma unroll
            for (int half = 0; half < 2; ++half) {
                const int lane = nl + 16 * ((vg & 1) * 2 + half);
                float4 o;
                o.x = acc[half * 4 + 0][q][jj];
                o.y = acc[half * 4 + 1][q][jj];
                o.z = acc[half * 4 + 2][q][jj];
                o.w = acc[half * 4 + 3][q][jj];
                size_t off = tilecol + ((size_t)t * 8 + vt * 2 + m) * 256 + lane * 4;
                *reinterpret_cast<float4*>(ws + off) = o;
            }
        }
    }
}

// ---------------- Kernel B: recurrence via 6-term bf16 MFMA emulation ----------------
__global__ __launch_bounds__(256, 2) void rnn_rec(
    const float* __restrict__ w2, const float* __restrict__ ws,
    float* __restrict__ out)
{
    // h splits, single-buffered: [split][n 0..31][k=v 0..63 (+8 pad)] bf16
    __shared__ __align__(16) unsigned short hsp[3][32][72];  // 13824 B

    const int tid  = threadIdx.x;
    const int w    = tid >> 6;         // wave id = v-tile
    const int lane = tid & 63;
    const int lg   = lane >> 4;
    const int nl   = lane & 15;
    const int bid  = blockIdx.x;
    const int nt   = bid & 31;
    const int b    = bid >> 5;
    const int n0   = nt * 32;

    // zero h splits (h0 = 0)
    for (int i = tid; i < 3456; i += 256)
        reinterpret_cast<unsigned int*>(hsp)[i] = 0u;

    // A-operand: w2 row-splits in registers. A[row=nl][k=lg*8+j], row_global = 16w+nl
    bf16x8 aw[2][3];
    #pragma unroll
    for (int kc = 0; kc < 2; ++kc) {
        const float* src = w2 + (size_t)(16 * w + nl) * 64 + kc * 32 + lg * 8;
        float wv[8];
        #pragma unroll
        for (int j = 0; j < 8; ++j) wv[j] = src[j];
        #pragma unroll
        for (int j = 0; j < 8; ++j) {
            unsigned short h, m, l;
            split3(wv[j], h, m, l);
            aw[kc][0][j] = (short)h; aw[kc][1][j] = (short)m; aw[kc][2][j] = (short)l;
        }
    }

    const size_t slab = ((size_t)(b * 32 + nt) * 64) * 2048;
    auto ldxw = [&](int t, int m) -> float4 {
        return *reinterpret_cast<const float4*>(
            ws + slab + ((size_t)t * 8 + w * 2 + m) * 256 + lane * 4);
    };

    __syncthreads();

    float4 xw0 = ldxw(0, 0), xw1 = ldxw(0, 1);
    unsigned int outw[2][4][8];        // [m][reg][t-pair] bf16-packed

    for (int tg = 0; tg < 4; ++tg) {
        #pragma unroll
        for (int j = 0; j < 16; ++j) {
            const int t = tg * 16 + j;

            // read B-fragments of h(t-1): B[k=(lg*8..)+kc*32][col=nl+16m]
            bf16x8 hb[3][2][2];
            #pragma unroll
            for (int s = 0; s < 3; ++s)
                #pragma unroll
                for (int kc = 0; kc < 2; ++kc)
                    #pragma unroll
                    for (int m = 0; m < 2; ++m)
                        hb[s][kc][m] = *reinterpret_cast<const bf16x8*>(
                            &hsp[s][nl + 16 * m][kc * 32 + lg * 8]);

            __syncthreads();   // all reads done before overwrite

            float4 nxt0 = xw0, nxt1 = xw1;
            if (t < 63) { nxt0 = ldxw(t + 1, 0); nxt1 = ldxw(t + 1, 1); }

            f32x4 acc0 = {xw0.x, xw0.y, xw0.z, xw0.w};
            f32x4 acc1 = {xw1.x, xw1.y, xw1.z, xw1.w};
            // 6 emulation terms, smallest first: (sA,sB) =
            // (2,0),(0,2),(1,1),(1,0),(0,1),(0,0)
            #pragma unroll
            for (int kc = 0; kc < 2; ++kc) {
                acc0 = __builtin_amdgcn_mfma_f32_16x16x32_bf16(aw[kc][2], hb[0][kc][0], acc0, 0, 0, 0);
                acc0 = __builtin_amdgcn_mfma_f32_16x16x32_bf16(aw[kc][0], hb[2][kc][0], acc0, 0, 0, 0);
                acc0 = __builtin_amdgcn_mfma_f32_16x16x32_bf16(aw[kc][1], hb[1][kc][0], acc0, 0, 0, 0);
                acc0 = __builtin_amdgcn_mfma_f32_16x16x32_bf16(aw[kc][1], hb[0][kc][0], acc0, 0, 0, 0);
                acc0 = __builtin_amdgcn_mfma_f32_16x16x32_bf16(aw[kc][0], hb[1][kc][0], acc0, 0, 0, 0);
                acc0 = __builtin_amdgcn_mfma_f32_16x16x32_bf16(aw[kc][0], hb[0][kc][0], acc0, 0, 0, 0);
                acc1 = __builtin_amdgcn_mfma_f32_16x16x32_bf16(aw[kc][2], hb[0][kc][1], acc1, 0, 0, 0);
                acc1 = __builtin_amdgcn_mfma_f32_16x16x32_bf16(aw[kc][0], hb[2][kc][1], acc1, 0, 0, 0);
                acc1 = __builtin_amdgcn_mfma_f32_16x16x32_bf16(aw[kc][1], hb[1][kc][1], acc1, 0, 0, 0);
                acc1 = __builtin_amdgcn_mfma_f32_16x16x32_bf16(aw[kc][1], hb[0][kc][1], acc1, 0, 0, 0);
                acc1 = __builtin_amdgcn_mfma_f32_16x16x32_bf16(aw[kc][0], hb[1][kc][1], acc1, 0, 0, 0);
                acc1 = __builtin_amdgcn_mfma_f32_16x16x32_bf16(aw[kc][0], hb[0][kc][1], acc1, 0, 0, 0);
            }

            // tanh + 3-way split + write splits of h(t)
            #pragma unroll
            for (int m = 0; m < 2; ++m) {
                unsigned short hs[3][4];
                #pragma unroll
                for (int r = 0; r < 4; ++r) {
                    float hv = tanh_fast(m == 0 ? acc0[r] : acc1[r]);
                    split3(hv, hs[0][r], hs[1][r], hs[2][r]);
                    if ((j & 1) == 0) outw[m][r][j >> 1] = (unsigned int)hs[0][r];
                    else              outw[m][r][j >> 1] |= ((unsigned int)hs[0][r]) << 16;
                }
                #pragma unroll
                for (int s = 0; s < 3; ++s) {
                    ushort4 pk = {hs[s][0], hs[s][1], hs[s][2], hs[s][3]};
                    *reinterpret_cast<ushort4*>(&hsp[s][nl + 16 * m][16 * w + lg * 4]) = pk;
                }
            }
            __syncthreads();   // h(t) visible

            xw0 = nxt0; xw1 = nxt1;
        }
        // flush 16 timesteps of output (full 64B lines per (v,n))
        #pragma unroll
        for (int m = 0; m < 2; ++m) {
            #pragma unroll
            for (int r = 0; r < 4; ++r) {
                const int v = 16 * w + lg * 4 + r;
                const int nn = n0 + nl + 16 * m;
                float* dst = out + ((size_t)(b * 64 + v) * 1024 + nn) * 64 + tg * 16;
                #pragma unroll
                for (int c = 0; c < 4; ++c) {
                    float4 o;
                    o.x = bf16_to_f32((unsigned short)(outw[m][r][2 * c] & 0xFFFFu));
                    o.y = bf16_to_f32((unsigned short)(outw[m][r][2 * c] >> 16));
                    o.z = bf16_to_f32((unsigned short)(outw[m][r][2 * c + 1] & 0xFFFFu));
                    o.w = bf16_to_f32((unsigned short)(outw[m][r][2 * c + 1] >> 16));
                    *reinterpret_cast<float4*>(dst + 4 * c) = o;
                }
            }
        }
    }
}

// ---------------- Fallback (round-1 kernel) if ws too small ----------------
__global__ __launch_bounds__(256, 2) void rnn_fused_kernel(
    const float* __restrict__ x, const float* __restrict__ w1,
    const float* __restrict__ b1, const float* __restrict__ w2,
    const float* __restrict__ b2, float* __restrict__ out)
{
    __shared__ __align__(16) float w1t[64][65];
    __shared__ __align__(16) float w2t[64][65];
    __shared__ __align__(16) float bsum[64];
    __shared__ __align__(16) float xs[4][64][32];
    __shared__ __align__(16) float Hs[64][32];

    const int tid = threadIdx.x;
    const int bid = blockIdx.x;
    const int b   = bid >> 5;
    const int n0  = (bid & 31) * 32;

    #pragma unroll
    for (int k = 0; k < 16; ++k) {
        const int idx = tid + 256 * k;
        const int v = idx >> 6, f = idx & 63;
        w1t[f][v] = w1[idx];
        w2t[f][v] = w2[idx];
    }
    if (tid < 64) bsum[tid] = b1[tid] + b2[tid];
    #pragma unroll
    for (int k = 0; k < 8; ++k) reinterpret_cast<float*>(Hs)[tid + 256 * k] = 0.0f;
    __syncthreads();

    const int v  = tid >> 2;
    const int ng = (tid & 3) * 8;
    const float bs = bsum[v];

    for (int tg = 0; tg < 16; ++tg) {
        #pragma unroll
        for (int k = 0; k < 8; ++k) {
            const int lin = tid + 256 * k;
            const int f = lin >> 5, n = lin & 31;
            const float4 xv = *reinterpret_cast<const float4*>(
                x + ((b * 64 + f) * 1024 + n0 + n) * 64 + tg * 4);
            xs[0][f][n] = xv.x; xs[1][f][n] = xv.y; xs[2][f][n] = xv.z; xs[3][f][n] = xv.w;
        }
        __syncthreads();
        #pragma unroll
        for (int tt = 0; tt < 4; ++tt) {
            const float* hsrc = (tt == 0) ? &Hs[0][0] : &xs[tt - 1][0][0];
            float acc[8];
            #pragma unroll
            for (int j = 0; j < 8; ++j) acc[j] = bs;
            #pragma unroll 4
            for (int f = 0; f < 64; ++f) {
                const float wv = w1t[f][v];
                const float4 xa = *reinterpret_cast<const float4*>(&xs[tt][f][ng]);
                const float4 xb = *reinterpret_cast<const float4*>(&xs[tt][f][ng + 4]);
                acc[0] = fmaf(wv, xa.x, acc[0]); acc[1] = fmaf(wv, xa.y, acc[1]);
                acc[2] = fmaf(wv, xa.z, acc[2]); acc[3] = fmaf(wv, xa.w, acc[3]);
                acc[4] = fmaf(wv, xb.x, acc[4]); acc[5] = fmaf(wv, xb.y, acc[5]);
                acc[6] = fmaf(wv, xb.z, acc[6]); acc[7] = fmaf(wv, xb.w, acc[7]);
            }
            #pragma unroll 4
            for (int u = 0; u < 64; ++u) {
                const float wv = w2t[u][v];
                const float4 ha = *reinterpret_cast<const float4*>(hsrc + u * 32 + ng);
                const float4 hb = *reinterpret_cast<const float4*>(hsrc + u * 32 + ng + 4);
                acc[0] = fmaf(wv, ha.x, acc[0]); acc[1] = fmaf(wv, ha.y, acc[1]);
                acc[2] = fmaf(wv, ha.z, acc[2]); acc[3] = fmaf(wv, ha.w, acc[3]);
                acc[4] = fmaf(wv, hb.x, acc[4]); acc[5] = fmaf(wv, hb.y, acc[5]);
                acc[6] = fmaf(wv, hb.z, acc[6]); acc[7] = fmaf(wv, hb.w, acc[7]);
            }
            float4 o0, o1;
            o0.x = tanh_fast(acc[0]); o0.y = tanh_fast(acc[1]);
            o0.z = tanh_fast(acc[2]); o0.w = tanh_fast(acc[3]);
            o1.x = tanh_fast(acc[4]); o1.y = tanh_fast(acc[5]);
            o1.z = tanh_fast(acc[6]); o1.w = tanh_fast(acc[7]);
            __syncthreads();
            *reinterpret_cast<float4*>(&xs[tt][v][ng])     = o0;
            *reinterpret_cast<float4*>(&xs[tt][v][ng + 4]) = o1;
            if (tt == 3) {
                *reinterpret_cast<float4*>(&Hs[v][ng])     = o0;
                *reinterpret_cast<float4*>(&Hs[v][ng + 4]) = o1;
            }
            __syncthreads();
        }
        #pragma unroll
        for (int k = 0; k < 8; ++k) {
            const int lin = tid + 256 * k;
            const int vv = lin >> 5, n = lin & 31;
            float4 o;
            o.x = xs[0][vv][n]; o.y = xs[1][vv][n]; o.z = xs[2][vv][n]; o.w = xs[3][vv][n];
            *reinterpret_cast<float4*>(
                out + ((b * 64 + vv) * 1024 + n0 + n) * 64 + tg * 4) = o;
        }
        __syncthreads();
    }
}

extern "C" void kernel_launch(void* const* d_in, const int* in_sizes, int n_in,
                              void* d_out, int out_size, void* d_ws, size_t ws_size,
                              hipStream_t stream) {
    const float* x  = (const float*)d_in[0];
    const float* w1 = (const float*)d_in[1];
    const float* b1 = (const float*)d_in[2];
    const float* w2 = (const float*)d_in[3];
    const float* b2 = (const float*)d_in[4];
    float* out = (float*)d_out;

    if (ws_size >= kWsNeed) {
        float* ws = (float*)d_ws;
        hipLaunchKernelGGL(xw_gemm, dim3(2048), dim3(256), 0, stream,
                           x, w1, b1, b2, ws);
        hipLaunchKernelGGL(rnn_rec, dim3(512), dim3(256), 0, stream,
                           w2, ws, out);
    } else {
        hipLaunchKernelGGL(rnn_fused_kernel, dim3(512), dim3(256), 0, stream,
                           x, w1, b1, w2, b2, out);
    }
}